// Round 13
// baseline (745.712 us; speedup 1.0000x reference)
//
#include <hip/hip_runtime.h>

typedef unsigned int u32;
typedef unsigned short u16;
typedef __attribute__((ext_vector_type(8))) __bf16 bf16x8;
typedef __attribute__((ext_vector_type(4))) float f32x4;

#define MFMA(a,b,c) __builtin_amdgcn_mfma_f32_16x16x32_bf16(a,b,c,0,0,0)

__device__ __forceinline__ float bf2f(u16 v){ return __uint_as_float(((u32)v) << 16); }
__device__ __forceinline__ u16 f2bf(float f){
  u32 u = __float_as_uint(f);
  u += 0x7fffu + ((u >> 16) & 1u);
  return (u16)(u >> 16);
}
__device__ __forceinline__ u32 pack2(float a, float b){
  return (u32)f2bf(a) | ((u32)f2bf(b) << 16);
}
// tanh-form GELU: max |diff vs exact erf-GELU| ~5e-4, below bf16 storage noise of h.
__device__ __forceinline__ float gelu_fast(float v){
  float t = v*(-1.5957691216f - 0.0713548163f*v*v);
  return v / (1.f + __expf(t));
}

// ---------------- workspace (u16 units): fragment-major bf16 weights, hi+lo ----------------
#define OQKV_HI 0
#define OQKV_LO 110592
#define OWP_HI  221184
#define OWP_LO  258048
#define OW1_HI  294912
#define OW1_LO  442368
#define OW2_HI  589824
#define OW2_LO  731136
#define NW_TOT  436224

__global__ void swin_unpack(const float* __restrict__ qkvw, const float* __restrict__ projw,
                            const float* __restrict__ w1, const float* __restrict__ w2,
                            u16* __restrict__ ws){
  int idx = blockIdx.x * 256 + threadIdx.x;
  if (idx >= NW_TOT) return;
  float val = 0.f; int hi, lo;
  if (idx < 110592){
    int t = idx, nt = t / 3072, r = t % 3072, kt = r >> 9, e = r & 511;
    int lane = e >> 3, j = e & 7;
    int n = nt*16 + (lane & 15), k = kt*32 + (lane >> 4)*8 + j;
    int p = n / 192, c = n - p*192;
    if (c < 180 && k < 180) val = qkvw[k*540 + p*180 + c];
    hi = OQKV_HI + t; lo = OQKV_LO + t;
  } else if (idx < 147456){
    int t = idx - 110592, nt = t / 3072, r = t % 3072, kt = r >> 9, e = r & 511;
    int lane = e >> 3, j = e & 7;
    int n = nt*16 + (lane & 15), k = kt*32 + (lane >> 4)*8 + j;
    if (n < 180 && k < 180) val = projw[k*180 + n];
    hi = OWP_HI + t; lo = OWP_LO + t;
  } else if (idx < 294912){
    int t = idx - 147456, nt = t / 3072, r = t % 3072, kt = r >> 9, e = r & 511;
    int lane = e >> 3, j = e & 7;
    int n = nt*16 + (lane & 15), k = kt*32 + (lane >> 4)*8 + j;
    if (n < 720 && k < 180) val = w1[k*720 + n];
    hi = OW1_HI + t; lo = OW1_LO + t;
  } else {
    int t = idx - 294912, nt = t / 11776, r = t % 11776, kt = r >> 9, e = r & 511;
    int lane = e >> 3, j = e & 7;
    int n = nt*16 + (lane & 15), k = kt*32 + (lane >> 4)*8 + j;
    if (n < 180 && k < 720) val = w2[k*180 + n];
    hi = OW2_HI + t; lo = OW2_LO + t;
  }
  u16 h = f2bf(val);
  ws[hi] = h;
  ws[lo] = f2bf(val - bf2f(h));
}

// ---------------- kernel 1: per-window LN1 + QKV + attn + proj + residual (512 thr, 8 waves) ----
// QKV/proj use 1-deep B prefetch: 2-deep measured a 312->434us regression (r12).
#define A_Y   0
#define A_Q   25600
#define A_K   51200
#define A_VT  76800
#define A_OLO 104448
#define A_P   130048
#define A_RB  148480

__global__ __launch_bounds__(512, 2) void swin_attn(
    const float* __restrict__ x, const float* __restrict__ n1s, const float* __restrict__ n1b,
    const u16* __restrict__ ws, const float* __restrict__ qkvb,
    const float* __restrict__ projb, float* __restrict__ out){
  __shared__ __align__(16) char sm[148736];
  const int tid = threadIdx.x;
  const int w8 = tid >> 6, l = tid & 63, l15 = l & 15, lq = l >> 4;
  const int mh = w8 >> 2, wc = w8 & 3;
  int* rb = (int*)(sm + A_RB);
  const f32x4 fz = {0.f, 0.f, 0.f, 0.f};

  if (tid < 64){
    int wb = blockIdx.x;
    int b = wb >> 10, wy = (wb >> 5) & 31, wx = wb & 31;
    rb[tid] = b*65536 + (wy*8 + (tid>>3))*256 + (wx*8 + (tid&7));
  }
  for (int i = tid; i < 3072; i += 512){
    int row = i / 48, t = i - row*48;
    if (t < 24){
      int buf = (t >= 12) ? A_K : A_Q; int tt = t % 12;
      *(u16*)(sm + buf + row*400 + ((tt>>1)*32 + 30 + (tt&1))*2) = 0;
    } else if (t < 36)
      *(u16*)(sm + A_OLO + row*400 + (180 + t - 24)*2) = 0;
    else
      *(u16*)(sm + A_Y + row*400 + (180 + t - 36)*2) = 0;
  }
  __syncthreads();

  // ---- LN1 ----
  {
    int r3 = l & 7, lq2 = l >> 3;
    int n = w8*8 + r3;
    const float4* px = (const float4*)(x + (size_t)rb[n]*180);
    float4 v[6];
    #pragma unroll
    for (int i = 0; i < 5; ++i) v[i] = px[lq2 + 8*i];
    v[5] = (lq2 < 5) ? px[lq2 + 40] : make_float4(0.f,0.f,0.f,0.f);
    float s = 0.f, ss = 0.f;
    #pragma unroll
    for (int i = 0; i < 6; ++i){
      s  += v[i].x + v[i].y + v[i].z + v[i].w;
      ss += v[i].x*v[i].x + v[i].y*v[i].y + v[i].z*v[i].z + v[i].w*v[i].w;
    }
    #pragma unroll
    for (int m = 8; m <= 32; m <<= 1){ s += __shfl_xor(s, m); ss += __shfl_xor(ss, m); }
    float mean = s * (1.f/180.f);
    float rstd = rsqrtf(ss * (1.f/180.f) - mean*mean + 1e-5f);
    u32* yr = (u32*)(sm + A_Y + n*400);
    const float4* s4 = (const float4*)n1s;
    const float4* b4 = (const float4*)n1b;
    #pragma unroll
    for (int i = 0; i < 6; ++i){
      if (i < 5 || lq2 < 5){
        int c4 = lq2 + 8*i;
        float4 sc = s4[c4], bi = b4[c4];
        float e0 = (v[i].x - mean)*rstd*sc.x + bi.x;
        float e1 = (v[i].y - mean)*rstd*sc.y + bi.y;
        float e2 = (v[i].z - mean)*rstd*sc.z + bi.z;
        float e3 = (v[i].w - mean)*rstd*sc.w + bi.w;
        yr[c4*2]     = pack2(e0, e1);
        yr[c4*2 + 1] = pack2(e2, e3);
      }
    }
  }
  __syncthreads();

  // ---- QKV: hi-only weights + 1-deep kt prefetch ----
  for (int ch = 0; ch < 3; ++ch){
    const int ntb = wc*9 + ch*3;
    f32x4 acc[2][3];
    #pragma unroll
    for (int m = 0; m < 2; ++m)
      #pragma unroll
      for (int i = 0; i < 3; ++i) acc[m][i] = fz;
    bf16x8 bcur[3];
    #pragma unroll
    for (int i = 0; i < 3; ++i)
      bcur[i] = *(const bf16x8*)(ws + OQKV_HI + ((ntb+i)*6 + 0)*512 + l*8);
    #pragma unroll
    for (int kt = 0; kt < 6; ++kt){
      bf16x8 bnxt[3];
      int ktn = (kt < 5) ? kt + 1 : kt;
      #pragma unroll
      for (int i = 0; i < 3; ++i)
        bnxt[i] = *(const bf16x8*)(ws + OQKV_HI + ((ntb+i)*6 + ktn)*512 + l*8);
      bf16x8 a[2];
      #pragma unroll
      for (int m = 0; m < 2; ++m)
        a[m] = *(const bf16x8*)(sm + A_Y + (mh*32 + m*16 + l15)*400 + kt*64 + lq*16);
      #pragma unroll
      for (int m = 0; m < 2; ++m)
        #pragma unroll
        for (int i = 0; i < 3; ++i)
          acc[m][i] = MFMA(a[m], bcur[i], acc[m][i]);
      #pragma unroll
      for (int i = 0; i < 3; ++i) bcur[i] = bnxt[i];
    }
    #pragma unroll
    for (int i = 0; i < 3; ++i){
      int n = (ntb + i)*16 + l15;
      int p = n / 192, c = n - p*192;
      if (c < 180){
        float bias = qkvb[p*180 + c];
        int h = c / 30, d = c - h*30;
        int colp = h*32 + d;
        #pragma unroll
        for (int m = 0; m < 2; ++m)
          #pragma unroll
          for (int r = 0; r < 4; ++r){
            float val = acc[m][i][r] + bias;
            int tok = mh*32 + m*16 + lq*4 + r;
            if (p == 0)      *(u16*)(sm + A_Q + tok*400 + colp*2) = f2bf(val * 0.18257418583505536f);
            else if (p == 1) *(u16*)(sm + A_K + tok*400 + colp*2) = f2bf(val);
            else             *(u16*)(sm + A_VT + colp*144 + tok*2) = f2bf(val);
          }
      }
    }
  }
  __syncthreads();

  // ---- attention ----
  {
    const int tq = w8 & 3, hbase = (w8 >> 2)*3;
    for (int h = hbase; h < hbase + 3; ++h){
      bf16x8 aq = *(const bf16x8*)(sm + A_Q + (tq*16 + l15)*400 + h*64 + lq*16);
      f32x4 s[4];
      #pragma unroll
      for (int nt = 0; nt < 4; ++nt){
        bf16x8 bk = *(const bf16x8*)(sm + A_K + (nt*16 + l15)*400 + h*64 + lq*16);
        s[nt] = MFMA(aq, bk, fz);
      }
      #pragma unroll
      for (int r = 0; r < 4; ++r){
        float mx = fmaxf(fmaxf(s[0][r], s[1][r]), fmaxf(s[2][r], s[3][r]));
        mx = fmaxf(mx, __shfl_xor(mx, 1));
        mx = fmaxf(mx, __shfl_xor(mx, 2));
        mx = fmaxf(mx, __shfl_xor(mx, 4));
        mx = fmaxf(mx, __shfl_xor(mx, 8));
        float e0 = __expf(s[0][r]-mx), e1 = __expf(s[1][r]-mx);
        float e2 = __expf(s[2][r]-mx), e3 = __expf(s[3][r]-mx);
        float sum = e0 + e1 + e2 + e3;
        sum += __shfl_xor(sum,1); sum += __shfl_xor(sum,2);
        sum += __shfl_xor(sum,4); sum += __shfl_xor(sum,8);
        float iv = 1.f / sum;
        char* pr = sm + A_P + w8*2304 + (lq*4 + r)*144 + l15*2;
        *(u16*)(pr)      = f2bf(e0 * iv);
        *(u16*)(pr + 32) = f2bf(e1 * iv);
        *(u16*)(pr + 64) = f2bf(e2 * iv);
        *(u16*)(pr + 96) = f2bf(e3 * iv);
      }
      asm volatile("s_waitcnt lgkmcnt(0)" ::: "memory");
      f32x4 o0 = fz, o1 = fz;
      #pragma unroll
      for (int kt = 0; kt < 2; ++kt){
        bf16x8 aP  = *(const bf16x8*)(sm + A_P + w8*2304 + l15*144 + kt*64 + lq*16);
        bf16x8 bv0 = *(const bf16x8*)(sm + A_VT + (h*32 + l15)*144 + kt*64 + lq*16);
        bf16x8 bv1 = *(const bf16x8*)(sm + A_VT + (h*32 + 16 + l15)*144 + kt*64 + lq*16);
        o0 = MFMA(aP, bv0, o0);
        o1 = MFMA(aP, bv1, o1);
      }
      #pragma unroll
      for (int r = 0; r < 4; ++r){
        int tok = tq*16 + lq*4 + r;
        {
          int col = h*30 + l15;
          float v = o0[r]; u16 ob = f2bf(v);
          *(u16*)(sm + A_Y   + tok*400 + col*2) = ob;
          *(u16*)(sm + A_OLO + tok*400 + col*2) = f2bf(v - bf2f(ob));
        }
        if (l15 < 14){
          int col = h*30 + 16 + l15;
          float v = o1[r]; u16 ob = f2bf(v);
          *(u16*)(sm + A_Y   + tok*400 + col*2) = ob;
          *(u16*)(sm + A_OLO + tok*400 + col*2) = f2bf(v - bf2f(ob));
        }
      }
    }
  }
  __syncthreads();

  // ---- proj: weight hi-only, activation hi+lo, 1-deep prefetch -> RES ----
  {
    f32x4 acc[2][3];
    #pragma unroll
    for (int m = 0; m < 2; ++m)
      #pragma unroll
      for (int i = 0; i < 3; ++i) acc[m][i] = fz;
    bf16x8 bcur[3];
    #pragma unroll
    for (int i = 0; i < 3; ++i)
      bcur[i] = *(const bf16x8*)(ws + OWP_HI + ((wc*3+i)*6 + 0)*512 + l*8);
    #pragma unroll
    for (int kt = 0; kt < 6; ++kt){
      bf16x8 bnxt[3];
      int ktn = (kt < 5) ? kt + 1 : kt;
      #pragma unroll
      for (int i = 0; i < 3; ++i)
        bnxt[i] = *(const bf16x8*)(ws + OWP_HI + ((wc*3+i)*6 + ktn)*512 + l*8);
      bf16x8 ah[2], al[2];
      #pragma unroll
      for (int m = 0; m < 2; ++m){
        ah[m] = *(const bf16x8*)(sm + A_Y   + (mh*32 + m*16 + l15)*400 + kt*64 + lq*16);
        al[m] = *(const bf16x8*)(sm + A_OLO + (mh*32 + m*16 + l15)*400 + kt*64 + lq*16);
      }
      #pragma unroll
      for (int m = 0; m < 2; ++m)
        #pragma unroll
        for (int i = 0; i < 3; ++i){
          acc[m][i] = MFMA(ah[m], bcur[i], acc[m][i]);
          acc[m][i] = MFMA(al[m], bcur[i], acc[m][i]);
        }
      #pragma unroll
      for (int i = 0; i < 3; ++i) bcur[i] = bnxt[i];
    }
    float* res = (float*)(sm + A_Q);
    #pragma unroll
    for (int i = 0; i < 3; ++i){
      int col = (wc*3 + i)*16 + l15;
      if (col < 180){
        float bias = projb[col];
        #pragma unroll
        for (int m = 0; m < 2; ++m)
          #pragma unroll
          for (int r = 0; r < 4; ++r)
            res[(mh*32 + m*16 + lq*4 + r)*180 + col] = acc[m][i][r] + bias;
      }
    }
  }
  __syncthreads();

  // ---- cooperative residual write ----
  {
    const float4* res4 = (const float4*)(sm + A_Q);
    for (int idx = tid; idx < 2880; idx += 512){
      int n = idx / 45, c4 = idx - n*45;
      size_t g4 = (size_t)rb[n]*45 + c4;
      float4 rv = res4[idx];
      float4 xv = ((const float4*)x)[g4];
      float4 o; o.x = rv.x + xv.x; o.y = rv.y + xv.y; o.z = rv.z + xv.z; o.w = rv.w + xv.w;
      ((float4*)out)[g4] = o;
    }
  }
}

// ---------------- kernel 2: LN2 + MLP(fast GELU) + residual (512 thr, 8 waves, hi-only W) ----
#define M_Y 0
#define M_G 25600

__global__ __launch_bounds__(512, 1) void swin_mlp(
    const float* __restrict__ n2s, const float* __restrict__ n2b,
    const u16* __restrict__ ws, const float* __restrict__ b1, const float* __restrict__ b2,
    float* __restrict__ out){
  __shared__ __align__(16) char sm[124928];
  const int tid = threadIdx.x;
  const int w8 = tid >> 6, l = tid & 63, l15 = l & 15, lq = l >> 4;
  const size_t base = (size_t)blockIdx.x * (64*180);
  const f32x4 fz = {0.f, 0.f, 0.f, 0.f};

  for (int i = tid; i < 768; i += 512){
    int row = i / 12, col = 180 + i % 12;
    *(u16*)(sm + M_Y + row*400 + col*2) = 0;
  }
  // ---- LN2 ----
  {
    int r3 = l & 7, lq2 = l >> 3;
    int n = w8*8 + r3;
    const float4* px = (const float4*)(out + base + (size_t)n*180);
    float4 v[6];
    #pragma unroll
    for (int i = 0; i < 5; ++i) v[i] = px[lq2 + 8*i];
    v[5] = (lq2 < 5) ? px[lq2 + 40] : make_float4(0.f,0.f,0.f,0.f);
    float s = 0.f, ss = 0.f;
    #pragma unroll
    for (int i = 0; i < 6; ++i){
      s  += v[i].x + v[i].y + v[i].z + v[i].w;
      ss += v[i].x*v[i].x + v[i].y*v[i].y + v[i].z*v[i].z + v[i].w*v[i].w;
    }
    #pragma unroll
    for (int m = 8; m <= 32; m <<= 1){ s += __shfl_xor(s, m); ss += __shfl_xor(ss, m); }
    float mean = s * (1.f/180.f);
    float rstd = rsqrtf(ss * (1.f/180.f) - mean*mean + 1e-5f);
    u32* yr = (u32*)(sm + M_Y + n*400);
    const float4* s4 = (const float4*)n2s;
    const float4* b4 = (const float4*)n2b;
    #pragma unroll
    for (int i = 0; i < 6; ++i){
      if (i < 5 || lq2 < 5){
        int c4 = lq2 + 8*i;
        float4 sc = s4[c4], bi = b4[c4];
        float e0 = (v[i].x - mean)*rstd*sc.x + bi.x;
        float e1 = (v[i].y - mean)*rstd*sc.y + bi.y;
        float e2 = (v[i].z - mean)*rstd*sc.z + bi.z;
        float e3 = (v[i].w - mean)*rstd*sc.w + bi.w;
        yr[c4*2]     = pack2(e0, e1);
        yr[c4*2 + 1] = pack2(e2, e3);
      }
    }
  }
  __syncthreads();

  // ---- GEMM1 + fast GELU: wave w8 owns 6 nt in 2 chunks of 3; 2-deep prefetch ----
  for (int ch = 0; ch < 2; ++ch){
    const int ntb = w8*6 + ch*3;
    f32x4 acc[4][3];
    #pragma unroll
    for (int m = 0; m < 4; ++m)
      #pragma unroll
      for (int i = 0; i < 3; ++i) acc[m][i] = fz;
    bf16x8 wb0[3], wb1[3];
    #pragma unroll
    for (int i = 0; i < 3; ++i){
      wb0[i] = *(const bf16x8*)(ws + OW1_HI + ((ntb+i)*6 + 0)*512 + l*8);
      wb1[i] = *(const bf16x8*)(ws + OW1_HI + ((ntb+i)*6 + 1)*512 + l*8);
    }
    #pragma unroll
    for (int kt = 0; kt < 6; ++kt){
      bf16x8 wbn[3];
      if (kt + 2 < 6){
        #pragma unroll
        for (int i = 0; i < 3; ++i)
          wbn[i] = *(const bf16x8*)(ws + OW1_HI + ((ntb+i)*6 + kt + 2)*512 + l*8);
      }
      bf16x8 a[4];
      #pragma unroll
      for (int m = 0; m < 4; ++m)
        a[m] = *(const bf16x8*)(sm + M_Y + (m*16 + l15)*400 + kt*64 + lq*16);
      #pragma unroll
      for (int m = 0; m < 4; ++m)
        #pragma unroll
        for (int i = 0; i < 3; ++i)
          acc[m][i] = MFMA(a[m], wb0[i], acc[m][i]);
      #pragma unroll
      for (int i = 0; i < 3; ++i){ wb0[i] = wb1[i]; if (kt + 2 < 6) wb1[i] = wbn[i]; }
    }
    #pragma unroll
    for (int i = 0; i < 3; ++i){
      int gc = (ntb + i)*16 + l15;   // 0..767
      float bias = (gc < 720) ? b1[gc] : 0.f;
      #pragma unroll
      for (int m = 0; m < 4; ++m)
        #pragma unroll
        for (int r = 0; r < 4; ++r){
          float v = acc[m][i][r] + bias;
          float gel = (gc < 720) ? gelu_fast(v) : 0.f;
          *(u16*)(sm + M_G + (m*16 + lq*4 + r)*1552 + gc*2) = f2bf(gel);
        }
    }
  }
  __syncthreads();

  // ---- GEMM2: 23 kt; wave (mh2: 2 mt) x (wc4: 3 nt); 2-deep prefetch ----
  {
    const int mh2 = w8 >> 2, wc4 = w8 & 3;
    f32x4 acc2[2][3];
    #pragma unroll
    for (int m = 0; m < 2; ++m)
      #pragma unroll
      for (int i = 0; i < 3; ++i) acc2[m][i] = fz;
    bf16x8 wb0[3], wb1[3];
    #pragma unroll
    for (int i = 0; i < 3; ++i){
      wb0[i] = *(const bf16x8*)(ws + OW2_HI + ((wc4*3+i)*23 + 0)*512 + l*8);
      wb1[i] = *(const bf16x8*)(ws + OW2_HI + ((wc4*3+i)*23 + 1)*512 + l*8);
    }
    for (int kt = 0; kt < 23; ++kt){
      bf16x8 wbn[3];
      int ktn = (kt < 21) ? kt + 2 : 22;
      #pragma unroll
      for (int i = 0; i < 3; ++i)
        wbn[i] = *(const bf16x8*)(ws + OW2_HI + ((wc4*3+i)*23 + ktn)*512 + l*8);
      bf16x8 a[2];
      #pragma unroll
      for (int m = 0; m < 2; ++m)
        a[m] = *(const bf16x8*)(sm + M_G + (mh2*32 + m*16 + l15)*1552 + kt*64 + lq*16);
      #pragma unroll
      for (int m = 0; m < 2; ++m)
        #pragma unroll
        for (int i = 0; i < 3; ++i)
          acc2[m][i] = MFMA(a[m], wb0[i], acc2[m][i]);
      #pragma unroll
      for (int i = 0; i < 3; ++i){ wb0[i] = wb1[i]; wb1[i] = wbn[i]; }
    }
    __syncthreads();

    float* res = (float*)(sm + M_G);
    #pragma unroll
    for (int i = 0; i < 3; ++i){
      int col = (wc4*3 + i)*16 + l15;
      if (col < 180){
        float bias = b2[col];
        #pragma unroll
        for (int m = 0; m < 2; ++m)
          #pragma unroll
          for (int r = 0; r < 4; ++r)
            res[(mh2*32 + m*16 + lq*4 + r)*180 + col] = acc2[m][i][r] + bias;
      }
    }
  }
  __syncthreads();

  // ---- cooperative RMW ----
  {
    const float4* res4 = (const float4*)(sm + M_G);
    float4* og = (float4*)(out + base);
    for (int idx = tid; idx < 2880; idx += 512){
      float4 rv = res4[idx];
      float4 xv = og[idx];
      float4 o; o.x = rv.x + xv.x; o.y = rv.y + xv.y; o.z = rv.z + xv.z; o.w = rv.w + xv.w;
      og[idx] = o;
    }
  }
}

extern "C" void kernel_launch(void* const* d_in, const int* in_sizes, int n_in,
                              void* d_out, int out_size, void* d_ws, size_t ws_size,
                              hipStream_t stream){
  const float* x     = (const float*)d_in[0];
  const float* n1s   = (const float*)d_in[1];
  const float* n1b   = (const float*)d_in[2];
  const float* qkvw  = (const float*)d_in[3];
  const float* qkvb  = (const float*)d_in[4];
  const float* projw = (const float*)d_in[5];
  const float* projb = (const float*)d_in[6];
  const float* n2s   = (const float*)d_in[7];
  const float* n2b   = (const float*)d_in[8];
  const float* w1    = (const float*)d_in[9];
  const float* b1    = (const float*)d_in[10];
  const float* w2    = (const float*)d_in[11];
  const float* b2    = (const float*)d_in[12];
  float* outp = (float*)d_out;
  u16* wsp = (u16*)d_ws;

  swin_unpack<<<(NW_TOT + 255) / 256, 256, 0, stream>>>(qkvw, projw, w1, w2, wsp);
  swin_attn<<<4096, 512, 0, stream>>>(x, n1s, n1b, wsp, qkvb, projb, outp);
  swin_mlp<<<4096, 512, 0, stream>>>(n2s, n2b, wsp, b1, b2, outp);
}

// Round 14
// 696.661 us; speedup vs baseline: 1.0704x; 1.0704x over previous
//
#include <hip/hip_runtime.h>

typedef unsigned int u32;
typedef unsigned short u16;
typedef __attribute__((ext_vector_type(8))) __bf16 bf16x8;
typedef __attribute__((ext_vector_type(4))) float f32x4;

#define MFMA(a,b,c) __builtin_amdgcn_mfma_f32_16x16x32_bf16(a,b,c,0,0,0)

__device__ __forceinline__ float bf2f(u16 v){ return __uint_as_float(((u32)v) << 16); }
__device__ __forceinline__ u16 f2bf(float f){
  u32 u = __float_as_uint(f);
  u += 0x7fffu + ((u >> 16) & 1u);
  return (u16)(u >> 16);
}
__device__ __forceinline__ u32 pack2(float a, float b){
  return (u32)f2bf(a) | ((u32)f2bf(b) << 16);
}
// tanh-form GELU: max |diff vs exact erf-GELU| ~5e-4, below bf16 storage noise of h.
__device__ __forceinline__ float gelu_fast(float v){
  float t = v*(-1.5957691216f - 0.0713548163f*v*v);
  return v / (1.f + __expf(t));
}

// ---------------- workspace (u16 units): fragment-major bf16 weights, HI plane only ----------------
// QKV padded to 40 nt (640 cols; 576 valid, 540 real), others exact.
#define OQKV 0         // 40*6*512  = 122880
#define OWP  122880    // 12*6*512  =  36864
#define OW1  159744    // 48*6*512  = 147456
#define OW2  307200    // 12*23*512 = 141312
#define NW_TOT 448512

__global__ void swin_unpack(const float* __restrict__ qkvw, const float* __restrict__ projw,
                            const float* __restrict__ w1, const float* __restrict__ w2,
                            u16* __restrict__ ws){
  int idx = blockIdx.x * 256 + threadIdx.x;
  if (idx >= NW_TOT) return;
  float val = 0.f;
  if (idx < OWP){
    int t = idx, nt = t / 3072, r = t % 3072, kt = r >> 9, e = r & 511;
    int lane = e >> 3, j = e & 7;
    int n = nt*16 + (lane & 15), k = kt*32 + (lane >> 4)*8 + j;
    if (n < 576){
      int p = n / 192, c = n - p*192;
      if (c < 180 && k < 180) val = qkvw[k*540 + p*180 + c];
    }
  } else if (idx < OW1){
    int t = idx - OWP, nt = t / 3072, r = t % 3072, kt = r >> 9, e = r & 511;
    int lane = e >> 3, j = e & 7;
    int n = nt*16 + (lane & 15), k = kt*32 + (lane >> 4)*8 + j;
    if (n < 180 && k < 180) val = projw[k*180 + n];
  } else if (idx < OW2){
    int t = idx - OW1, nt = t / 3072, r = t % 3072, kt = r >> 9, e = r & 511;
    int lane = e >> 3, j = e & 7;
    int n = nt*16 + (lane & 15), k = kt*32 + (lane >> 4)*8 + j;
    if (n < 720 && k < 180) val = w1[k*720 + n];
  } else {
    int t = idx - OW2, nt = t / 11776, r = t % 11776, kt = r >> 9, e = r & 511;
    int lane = e >> 3, j = e & 7;
    int n = nt*16 + (lane & 15), k = kt*32 + (lane >> 4)*8 + j;
    if (n < 180 && k < 720) val = w2[k*180 + n];
  }
  ws[idx] = f2bf(val);
}

// ---------------- kernel 1: per-window LN1 + QKV + attn + proj + residual (512 thr, 8 waves) ----
// QKV: wave owns 5 nt x ALL 4 token-tiles (B-loads amortized 4x). Proj: act hi-only.
// LDS 123136B -> 1 block/CU, 8 waves = 2/SIMD. (512,1): no VGPR cap (<=256 keeps 8 waves/CU).
#define A_Y   0        // 64 x 400B (LN'd y -> o)
#define A_Q   25600    // 64 x 400B (reused with K as fp32 RES[64][180] after attention)
#define A_K   51200    // 64 x 400B
#define A_VT  76800    // 192 x 144B
#define A_P   104448   // 8 waves x 2304B
#define A_RB  122880   // 64 ints

__global__ __launch_bounds__(512, 1) void swin_attn(
    const float* __restrict__ x, const float* __restrict__ n1s, const float* __restrict__ n1b,
    const u16* __restrict__ ws, const float* __restrict__ qkvb,
    const float* __restrict__ projb, float* __restrict__ out){
  __shared__ __align__(16) char sm[123136];
  const int tid = threadIdx.x;
  const int w8 = tid >> 6, l = tid & 63, l15 = l & 15, lq = l >> 4;
  const int mh = w8 >> 2, wc = w8 & 3;
  int* rb = (int*)(sm + A_RB);
  const f32x4 fz = {0.f, 0.f, 0.f, 0.f};

  if (tid < 64){
    int wb = blockIdx.x;
    int b = wb >> 10, wy = (wb >> 5) & 31, wx = wb & 31;
    rb[tid] = b*65536 + (wy*8 + (tid>>3))*256 + (wx*8 + (tid&7));
  }
  // zero pads: Q/K head-pad cols h*32+{30,31}; Y cols 180..191
  for (int i = tid; i < 2304; i += 512){
    int row = i / 36, t = i - row*36;
    if (t < 24){
      int buf = (t >= 12) ? A_K : A_Q; int tt = t % 12;
      *(u16*)(sm + buf + row*400 + ((tt>>1)*32 + 30 + (tt&1))*2) = 0;
    } else
      *(u16*)(sm + A_Y + row*400 + (180 + t - 24)*2) = 0;
  }
  __syncthreads();

  // ---- LN1 ----
  {
    int r3 = l & 7, lq2 = l >> 3;
    int n = w8*8 + r3;
    const float4* px = (const float4*)(x + (size_t)rb[n]*180);
    float4 v[6];
    #pragma unroll
    for (int i = 0; i < 5; ++i) v[i] = px[lq2 + 8*i];
    v[5] = (lq2 < 5) ? px[lq2 + 40] : make_float4(0.f,0.f,0.f,0.f);
    float s = 0.f, ss = 0.f;
    #pragma unroll
    for (int i = 0; i < 6; ++i){
      s  += v[i].x + v[i].y + v[i].z + v[i].w;
      ss += v[i].x*v[i].x + v[i].y*v[i].y + v[i].z*v[i].z + v[i].w*v[i].w;
    }
    #pragma unroll
    for (int m = 8; m <= 32; m <<= 1){ s += __shfl_xor(s, m); ss += __shfl_xor(ss, m); }
    float mean = s * (1.f/180.f);
    float rstd = rsqrtf(ss * (1.f/180.f) - mean*mean + 1e-5f);
    u32* yr = (u32*)(sm + A_Y + n*400);
    const float4* s4 = (const float4*)n1s;
    const float4* b4 = (const float4*)n1b;
    #pragma unroll
    for (int i = 0; i < 6; ++i){
      if (i < 5 || lq2 < 5){
        int c4 = lq2 + 8*i;
        float4 sc = s4[c4], bi = b4[c4];
        float e0 = (v[i].x - mean)*rstd*sc.x + bi.x;
        float e1 = (v[i].y - mean)*rstd*sc.y + bi.y;
        float e2 = (v[i].z - mean)*rstd*sc.z + bi.z;
        float e3 = (v[i].w - mean)*rstd*sc.w + bi.w;
        yr[c4*2]     = pack2(e0, e1);
        yr[c4*2 + 1] = pack2(e2, e3);
      }
    }
  }
  __syncthreads();

  // ---- QKV: wave w8 owns 5 nt (of 40, padded), all 64 tokens; 1-deep prefetch ----
  {
    const int ntb = w8*5;
    f32x4 acc[4][5];
    #pragma unroll
    for (int m = 0; m < 4; ++m)
      #pragma unroll
      for (int i = 0; i < 5; ++i) acc[m][i] = fz;
    bf16x8 bcur[5];
    #pragma unroll
    for (int i = 0; i < 5; ++i)
      bcur[i] = *(const bf16x8*)(ws + OQKV + ((ntb+i)*6 + 0)*512 + l*8);
    #pragma unroll
    for (int kt = 0; kt < 6; ++kt){
      bf16x8 bnxt[5];
      if (kt < 5){
        #pragma unroll
        for (int i = 0; i < 5; ++i)
          bnxt[i] = *(const bf16x8*)(ws + OQKV + ((ntb+i)*6 + kt + 1)*512 + l*8);
      }
      bf16x8 a[4];
      #pragma unroll
      for (int m = 0; m < 4; ++m)
        a[m] = *(const bf16x8*)(sm + A_Y + (m*16 + l15)*400 + kt*64 + lq*16);
      #pragma unroll
      for (int m = 0; m < 4; ++m)
        #pragma unroll
        for (int i = 0; i < 5; ++i)
          acc[m][i] = MFMA(a[m], bcur[i], acc[m][i]);
      if (kt < 5){
        #pragma unroll
        for (int i = 0; i < 5; ++i) bcur[i] = bnxt[i];
      }
    }
    #pragma unroll
    for (int i = 0; i < 5; ++i){
      int n = (ntb + i)*16 + l15;
      if (n < 576){
        int p = n / 192, c = n - p*192;
        if (c < 180){
          float bias = qkvb[p*180 + c];
          int h = c / 30, d = c - h*30;
          int colp = h*32 + d;
          #pragma unroll
          for (int m = 0; m < 4; ++m)
            #pragma unroll
            for (int r = 0; r < 4; ++r){
              float val = acc[m][i][r] + bias;
              int tok = m*16 + lq*4 + r;
              if (p == 0)      *(u16*)(sm + A_Q + tok*400 + colp*2) = f2bf(val * 0.18257418583505536f);
              else if (p == 1) *(u16*)(sm + A_K + tok*400 + colp*2) = f2bf(val);
              else             *(u16*)(sm + A_VT + colp*144 + tok*2) = f2bf(val);
            }
        }
      }
    }
  }
  __syncthreads();

  // ---- attention: wave (tq = w8&3, heads (w8>>2)*3 ..+2); o -> A_Y (hi only) ----
  {
    const int tq = w8 & 3, hbase = (w8 >> 2)*3;
    for (int h = hbase; h < hbase + 3; ++h){
      bf16x8 aq = *(const bf16x8*)(sm + A_Q + (tq*16 + l15)*400 + h*64 + lq*16);
      f32x4 s[4];
      #pragma unroll
      for (int nt = 0; nt < 4; ++nt){
        bf16x8 bk = *(const bf16x8*)(sm + A_K + (nt*16 + l15)*400 + h*64 + lq*16);
        s[nt] = MFMA(aq, bk, fz);
      }
      #pragma unroll
      for (int r = 0; r < 4; ++r){
        float mx = fmaxf(fmaxf(s[0][r], s[1][r]), fmaxf(s[2][r], s[3][r]));
        mx = fmaxf(mx, __shfl_xor(mx, 1));
        mx = fmaxf(mx, __shfl_xor(mx, 2));
        mx = fmaxf(mx, __shfl_xor(mx, 4));
        mx = fmaxf(mx, __shfl_xor(mx, 8));
        float e0 = __expf(s[0][r]-mx), e1 = __expf(s[1][r]-mx);
        float e2 = __expf(s[2][r]-mx), e3 = __expf(s[3][r]-mx);
        float sum = e0 + e1 + e2 + e3;
        sum += __shfl_xor(sum,1); sum += __shfl_xor(sum,2);
        sum += __shfl_xor(sum,4); sum += __shfl_xor(sum,8);
        float iv = 1.f / sum;
        char* pr = sm + A_P + w8*2304 + (lq*4 + r)*144 + l15*2;
        *(u16*)(pr)      = f2bf(e0 * iv);
        *(u16*)(pr + 32) = f2bf(e1 * iv);
        *(u16*)(pr + 64) = f2bf(e2 * iv);
        *(u16*)(pr + 96) = f2bf(e3 * iv);
      }
      asm volatile("s_waitcnt lgkmcnt(0)" ::: "memory");
      f32x4 o0 = fz, o1 = fz;
      #pragma unroll
      for (int kt = 0; kt < 2; ++kt){
        bf16x8 aP  = *(const bf16x8*)(sm + A_P + w8*2304 + l15*144 + kt*64 + lq*16);
        bf16x8 bv0 = *(const bf16x8*)(sm + A_VT + (h*32 + l15)*144 + kt*64 + lq*16);
        bf16x8 bv1 = *(const bf16x8*)(sm + A_VT + (h*32 + 16 + l15)*144 + kt*64 + lq*16);
        o0 = MFMA(aP, bv0, o0);
        o1 = MFMA(aP, bv1, o1);
      }
      #pragma unroll
      for (int r = 0; r < 4; ++r){
        int tok = tq*16 + lq*4 + r;
        {
          int col = h*30 + l15;
          *(u16*)(sm + A_Y + tok*400 + col*2) = f2bf(o0[r]);
        }
        if (l15 < 14){
          int col = h*30 + 16 + l15;
          *(u16*)(sm + A_Y + tok*400 + col*2) = f2bf(o1[r]);
        }
      }
    }
  }
  __syncthreads();

  // ---- proj: weight hi-only, activation hi-only, 1-deep prefetch -> RES (fp32, Q+K region) ----
  {
    f32x4 acc[2][3];
    #pragma unroll
    for (int m = 0; m < 2; ++m)
      #pragma unroll
      for (int i = 0; i < 3; ++i) acc[m][i] = fz;
    bf16x8 bcur[3];
    #pragma unroll
    for (int i = 0; i < 3; ++i)
      bcur[i] = *(const bf16x8*)(ws + OWP + ((wc*3+i)*6 + 0)*512 + l*8);
    #pragma unroll
    for (int kt = 0; kt < 6; ++kt){
      bf16x8 bnxt[3];
      int ktn = (kt < 5) ? kt + 1 : kt;
      #pragma unroll
      for (int i = 0; i < 3; ++i)
        bnxt[i] = *(const bf16x8*)(ws + OWP + ((wc*3+i)*6 + ktn)*512 + l*8);
      bf16x8 ah[2];
      #pragma unroll
      for (int m = 0; m < 2; ++m)
        ah[m] = *(const bf16x8*)(sm + A_Y + (mh*32 + m*16 + l15)*400 + kt*64 + lq*16);
      #pragma unroll
      for (int m = 0; m < 2; ++m)
        #pragma unroll
        for (int i = 0; i < 3; ++i)
          acc[m][i] = MFMA(ah[m], bcur[i], acc[m][i]);
      #pragma unroll
      for (int i = 0; i < 3; ++i) bcur[i] = bnxt[i];
    }
    float* res = (float*)(sm + A_Q);
    #pragma unroll
    for (int i = 0; i < 3; ++i){
      int col = (wc*3 + i)*16 + l15;
      if (col < 180){
        float bias = projb[col];
        #pragma unroll
        for (int m = 0; m < 2; ++m)
          #pragma unroll
          for (int r = 0; r < 4; ++r)
            res[(mh*32 + m*16 + lq*4 + r)*180 + col] = acc[m][i][r] + bias;
      }
    }
  }
  __syncthreads();

  // ---- cooperative residual write: out = RES + x (float4) ----
  {
    const float4* res4 = (const float4*)(sm + A_Q);
    for (int idx = tid; idx < 2880; idx += 512){
      int n = idx / 45, c4 = idx - n*45;
      size_t g4 = (size_t)rb[n]*45 + c4;
      float4 rv = res4[idx];
      float4 xv = ((const float4*)x)[g4];
      float4 o; o.x = rv.x + xv.x; o.y = rv.y + xv.y; o.z = rv.z + xv.z; o.w = rv.w + xv.w;
      ((float4*)out)[g4] = o;
    }
  }
}

// ---------------- kernel 2: LN2 + MLP(fast GELU) + residual (512 thr, 8 waves, hi-only W) ----
#define M_Y 0
#define M_G 25600

__global__ __launch_bounds__(512, 1) void swin_mlp(
    const float* __restrict__ n2s, const float* __restrict__ n2b,
    const u16* __restrict__ ws, const float* __restrict__ b1, const float* __restrict__ b2,
    float* __restrict__ out){
  __shared__ __align__(16) char sm[124928];
  const int tid = threadIdx.x;
  const int w8 = tid >> 6, l = tid & 63, l15 = l & 15, lq = l >> 4;
  const size_t base = (size_t)blockIdx.x * (64*180);
  const f32x4 fz = {0.f, 0.f, 0.f, 0.f};

  for (int i = tid; i < 768; i += 512){
    int row = i / 12, col = 180 + i % 12;
    *(u16*)(sm + M_Y + row*400 + col*2) = 0;
  }
  // ---- LN2 ----
  {
    int r3 = l & 7, lq2 = l >> 3;
    int n = w8*8 + r3;
    const float4* px = (const float4*)(out + base + (size_t)n*180);
    float4 v[6];
    #pragma unroll
    for (int i = 0; i < 5; ++i) v[i] = px[lq2 + 8*i];
    v[5] = (lq2 < 5) ? px[lq2 + 40] : make_float4(0.f,0.f,0.f,0.f);
    float s = 0.f, ss = 0.f;
    #pragma unroll
    for (int i = 0; i < 6; ++i){
      s  += v[i].x + v[i].y + v[i].z + v[i].w;
      ss += v[i].x*v[i].x + v[i].y*v[i].y + v[i].z*v[i].z + v[i].w*v[i].w;
    }
    #pragma unroll
    for (int m = 8; m <= 32; m <<= 1){ s += __shfl_xor(s, m); ss += __shfl_xor(ss, m); }
    float mean = s * (1.f/180.f);
    float rstd = rsqrtf(ss * (1.f/180.f) - mean*mean + 1e-5f);
    u32* yr = (u32*)(sm + M_Y + n*400);
    const float4* s4 = (const float4*)n2s;
    const float4* b4 = (const float4*)n2b;
    #pragma unroll
    for (int i = 0; i < 6; ++i){
      if (i < 5 || lq2 < 5){
        int c4 = lq2 + 8*i;
        float4 sc = s4[c4], bi = b4[c4];
        float e0 = (v[i].x - mean)*rstd*sc.x + bi.x;
        float e1 = (v[i].y - mean)*rstd*sc.y + bi.y;
        float e2 = (v[i].z - mean)*rstd*sc.z + bi.z;
        float e3 = (v[i].w - mean)*rstd*sc.w + bi.w;
        yr[c4*2]     = pack2(e0, e1);
        yr[c4*2 + 1] = pack2(e2, e3);
      }
    }
  }
  __syncthreads();

  // ---- GEMM1 + fast GELU: wave w8 owns 6 nt in 2 chunks of 3; 2-deep prefetch ----
  for (int ch = 0; ch < 2; ++ch){
    const int ntb = w8*6 + ch*3;
    f32x4 acc[4][3];
    #pragma unroll
    for (int m = 0; m < 4; ++m)
      #pragma unroll
      for (int i = 0; i < 3; ++i) acc[m][i] = fz;
    bf16x8 wb0[3], wb1[3];
    #pragma unroll
    for (int i = 0; i < 3; ++i){
      wb0[i] = *(const bf16x8*)(ws + OW1 + ((ntb+i)*6 + 0)*512 + l*8);
      wb1[i] = *(const bf16x8*)(ws + OW1 + ((ntb+i)*6 + 1)*512 + l*8);
    }
    #pragma unroll
    for (int kt = 0; kt < 6; ++kt){
      bf16x8 wbn[3];
      if (kt + 2 < 6){
        #pragma unroll
        for (int i = 0; i < 3; ++i)
          wbn[i] = *(const bf16x8*)(ws + OW1 + ((ntb+i)*6 + kt + 2)*512 + l*8);
      }
      bf16x8 a[4];
      #pragma unroll
      for (int m = 0; m < 4; ++m)
        a[m] = *(const bf16x8*)(sm + M_Y + (m*16 + l15)*400 + kt*64 + lq*16);
      #pragma unroll
      for (int m = 0; m < 4; ++m)
        #pragma unroll
        for (int i = 0; i < 3; ++i)
          acc[m][i] = MFMA(a[m], wb0[i], acc[m][i]);
      #pragma unroll
      for (int i = 0; i < 3; ++i){ wb0[i] = wb1[i]; if (kt + 2 < 6) wb1[i] = wbn[i]; }
    }
    #pragma unroll
    for (int i = 0; i < 3; ++i){
      int gc = (ntb + i)*16 + l15;   // 0..767
      float bias = (gc < 720) ? b1[gc] : 0.f;
      #pragma unroll
      for (int m = 0; m < 4; ++m)
        #pragma unroll
        for (int r = 0; r < 4; ++r){
          float v = acc[m][i][r] + bias;
          float gel = (gc < 720) ? gelu_fast(v) : 0.f;
          *(u16*)(sm + M_G + (m*16 + lq*4 + r)*1552 + gc*2) = f2bf(gel);
        }
    }
  }
  __syncthreads();

  // ---- GEMM2: 23 kt; wave (mh2: 2 mt) x (wc4: 3 nt); 2-deep prefetch ----
  {
    const int mh2 = w8 >> 2, wc4 = w8 & 3;
    f32x4 acc2[2][3];
    #pragma unroll
    for (int m = 0; m < 2; ++m)
      #pragma unroll
      for (int i = 0; i < 3; ++i) acc2[m][i] = fz;
    bf16x8 wb0[3], wb1[3];
    #pragma unroll
    for (int i = 0; i < 3; ++i){
      wb0[i] = *(const bf16x8*)(ws + OW2 + ((wc4*3+i)*23 + 0)*512 + l*8);
      wb1[i] = *(const bf16x8*)(ws + OW2 + ((wc4*3+i)*23 + 1)*512 + l*8);
    }
    for (int kt = 0; kt < 23; ++kt){
      bf16x8 wbn[3];
      int ktn = (kt < 21) ? kt + 2 : 22;
      #pragma unroll
      for (int i = 0; i < 3; ++i)
        wbn[i] = *(const bf16x8*)(ws + OW2 + ((wc4*3+i)*23 + ktn)*512 + l*8);
      bf16x8 a[2];
      #pragma unroll
      for (int m = 0; m < 2; ++m)
        a[m] = *(const bf16x8*)(sm + M_G + (mh2*32 + m*16 + l15)*1552 + kt*64 + lq*16);
      #pragma unroll
      for (int m = 0; m < 2; ++m)
        #pragma unroll
        for (int i = 0; i < 3; ++i)
          acc2[m][i] = MFMA(a[m], wb0[i], acc2[m][i]);
      #pragma unroll
      for (int i = 0; i < 3; ++i){ wb0[i] = wb1[i]; wb1[i] = wbn[i]; }
    }
    __syncthreads();

    float* res = (float*)(sm + M_G);
    #pragma unroll
    for (int i = 0; i < 3; ++i){
      int col = (wc4*3 + i)*16 + l15;
      if (col < 180){
        float bias = b2[col];
        #pragma unroll
        for (int m = 0; m < 2; ++m)
          #pragma unroll
          for (int r = 0; r < 4; ++r)
            res[(mh2*32 + m*16 + lq*4 + r)*180 + col] = acc2[m][i][r] + bias;
      }
    }
  }
  __syncthreads();

  // ---- cooperative RMW ----
  {
    const float4* res4 = (const float4*)(sm + M_G);
    float4* og = (float4*)(out + base);
    for (int idx = tid; idx < 2880; idx += 512){
      float4 rv = res4[idx];
      float4 xv = og[idx];
      float4 o; o.x = rv.x + xv.x; o.y = rv.y + xv.y; o.z = rv.z + xv.z; o.w = rv.w + xv.w;
      og[idx] = o;
    }
  }
}

extern "C" void kernel_launch(void* const* d_in, const int* in_sizes, int n_in,
                              void* d_out, int out_size, void* d_ws, size_t ws_size,
                              hipStream_t stream){
  const float* x     = (const float*)d_in[0];
  const float* n1s   = (const float*)d_in[1];
  const float* n1b   = (const float*)d_in[2];
  const float* qkvw  = (const float*)d_in[3];
  const float* qkvb  = (const float*)d_in[4];
  const float* projw = (const float*)d_in[5];
  const float* projb = (const float*)d_in[6];
  const float* n2s   = (const float*)d_in[7];
  const float* n2b   = (const float*)d_in[8];
  const float* w1    = (const float*)d_in[9];
  const float* b1    = (const float*)d_in[10];
  const float* w2    = (const float*)d_in[11];
  const float* b2    = (const float*)d_in[12];
  float* outp = (float*)d_out;
  u16* wsp = (u16*)d_ws;

  swin_unpack<<<(NW_TOT + 255) / 256, 256, 0, stream>>>(qkvw, projw, w1, w2, wsp);
  swin_attn<<<4096, 512, 0, stream>>>(x, n1s, n1b, wsp, qkvb, projb, outp);
  swin_mlp<<<4096, 512, 0, stream>>>(n2s, n2b, wsp, b1, b2, outp);
}